// Round 4
// baseline (479.718 us; speedup 1.0000x reference)
//
#include <hip/hip_runtime.h>

typedef unsigned short u16;
typedef __bf16  bf16x8 __attribute__((ext_vector_type(8)));
typedef float   f32x4  __attribute__((ext_vector_type(4)));
typedef u16     u16x8  __attribute__((ext_vector_type(8)));
typedef u16     u16x4  __attribute__((ext_vector_type(4)));

#define QSCALE 0.12751744545f   // log2(e)/sqrt(128)

// ---------------------------------------------------------------------------
// helpers
// ---------------------------------------------------------------------------
__device__ __forceinline__ u16 f2b(float f) {               // f32 -> bf16 (RNE)
    unsigned u = __float_as_uint(f);
    unsigned r = u + 0x7FFFu + ((u >> 16) & 1u);
    return (u16)(r >> 16);
}
__device__ __forceinline__ void async16(const u16* g, u16* l) {
    // lane L's 16B land at (wave-uniform l) + L*16; global src addr is per-lane
    __builtin_amdgcn_global_load_lds(
        (__attribute__((address_space(1))) void*)(u16*)g,
        (__attribute__((address_space(3))) void*)l, 16, 0, 0);
}

// ---------------------------------------------------------------------------
// fp32 -> bf16 convert (float4 per thread)
// ---------------------------------------------------------------------------
__global__ void cvt_f32_bf16(const float* __restrict__ in, u16* __restrict__ out, int n4) {
    int i = blockIdx.x * blockDim.x + threadIdx.x;
    if (i >= n4) return;
    float4 f = ((const float4*)in)[i];
    u16x4 o;
    o[0] = f2b(f.x); o[1] = f2b(f.y); o[2] = f2b(f.z); o[3] = f2b(f.w);
    *(u16x4*)(out + (size_t)i * 4) = o;
}

// wqkv convert with q-row pre-scale folded in (rows with (row%384)<128 are q)
__global__ void cvt_wqkv(const float* __restrict__ in, u16* __restrict__ out, int n4) {
    int i = blockIdx.x * blockDim.x + threadIdx.x;
    if (i >= n4) return;
    int row = i >> 9;                       // 512 float4 per 2048-elem row
    float s = ((row % 384) < 128) ? QSCALE : 1.0f;
    float4 f = ((const float4*)in)[i];
    u16x4 o;
    o[0] = f2b(f.x * s); o[1] = f2b(f.y * s); o[2] = f2b(f.z * s); o[3] = f2b(f.w * s);
    *(u16x4*)(out + (size_t)i * 4) = o;
}

// ---------------------------------------------------------------------------
// bf16 NT GEMM, 128x128 tile, 4 waves, 3-slot K32 ring, counted vmcnt(4),
// swizzled LDS (chunk ^= (row>>1)&3 folds to per-lane constant).
// K = 2048 (both uses). 3 blocks/CU resident (48 KiB LDS, 64 AGPR acc).
// mode 0: fused QKV scatter epilogue (grid 48 x 32)
// mode 1: f32 output with row remap (grid 16 x 32)
// ---------------------------------------------------------------------------
__global__ __launch_bounds__(256) void gemm_ring(
    const u16* __restrict__ A, const u16* __restrict__ B,
    const float* __restrict__ bias, void* __restrict__ C,
    u16* __restrict__ qb, u16* __restrict__ kb, u16* __restrict__ vb,
    int mode)
{
    constexpr int K  = 2048;
    constexpr int NS = 64;                   // K/32 subtiles
    __shared__ u16 lds[24576];               // 3 slots x (A[128][32] | B[128][32]) = 48 KiB

    const int tid = threadIdx.x, wave = tid >> 6, lane = tid & 63;
    const int lg = lane >> 4, lm = lane & 15;
    const int wm = (wave & 1) * 64, wn = (wave >> 1) * 64;

    const u16* Ab = A + (size_t)(blockIdx.y * 128) * K;
    const u16* Bb = B + (size_t)(blockIdx.x * 128) * K;

    // staging: 16 x 1KiB chunks per subtile (A: cc 0..7, B: 8..15); wave owns 4
    const int srow = lane >> 2;
    const int scs  = ((lane & 3) ^ ((lane >> 3) & 3)) * 8;   // swizzled src col (u16)

    auto stage_h = [&](int s_, int slot, int j0) {   // 2 chunks
        size_t k0 = (size_t)s_ * 32;
        for (int j = j0; j < j0 + 2; j++) {
            int cc = wave + 4 * j;                   // 0..15
            const u16* src = (cc < 8) ? Ab : Bb;
            int c8 = cc & 7;
            async16(src + (size_t)(c8 * 16 + srow) * K + k0 + scs,
                    &lds[slot * 8192 + (cc < 8 ? 0 : 4096) + c8 * 512]);
        }
    };

    // fragment read offset swizzle (per-lane constant)
    const int coff = (lg ^ ((lm >> 1) & 3)) * 8;

    f32x4 acc[4][4];
    for (int i = 0; i < 4; i++)
        for (int j = 0; j < 4; j++)
            acc[i][j] = (f32x4){0.f, 0.f, 0.f, 0.f};

    // prologue: stage subtiles 0,1; wait for 0 (leave 1's 4 loads in flight)
    stage_h(0, 0, 0); stage_h(0, 0, 2);
    stage_h(1, 1, 0); stage_h(1, 1, 2);
    asm volatile("s_waitcnt vmcnt(4)" ::: "memory");
    __builtin_amdgcn_s_barrier();

    int slc = 0;                              // slot of current subtile
    for (int s = 0; s < NS; s++) {
        const u16* sa = &lds[slc * 8192];
        const u16* sb = sa + 4096;
        int st = slc + 2; if (st >= 3) st -= 3;   // slot for s+2

        bf16x8 af[4], bf[4];
        // ---- phase 1: af0-3 + bf0-1, stage half of s+2 ----
        for (int i = 0; i < 4; i++) af[i] = *(const bf16x8*)&sa[(wm + i * 16 + lm) * 32 + coff];
        for (int j = 0; j < 2; j++) bf[j] = *(const bf16x8*)&sb[(wn + j * 16 + lm) * 32 + coff];
        if (s + 2 < NS) stage_h(s + 2, st, 0);
        __builtin_amdgcn_s_barrier();
        __builtin_amdgcn_s_setprio(1);
        for (int i = 0; i < 4; i++)
            for (int j = 0; j < 2; j++)
                acc[i][j] = __builtin_amdgcn_mfma_f32_16x16x32_bf16(af[i], bf[j], acc[i][j], 0, 0, 0);
        __builtin_amdgcn_s_setprio(0);
        __builtin_amdgcn_s_barrier();

        // ---- phase 2: bf2-3, stage other half of s+2 ----
        for (int j = 2; j < 4; j++) bf[j] = *(const bf16x8*)&sb[(wn + j * 16 + lm) * 32 + coff];
        if (s + 2 < NS) stage_h(s + 2, st, 2);
        __builtin_amdgcn_s_barrier();
        __builtin_amdgcn_s_setprio(1);
        for (int i = 0; i < 4; i++)
            for (int j = 2; j < 4; j++)
                acc[i][j] = __builtin_amdgcn_mfma_f32_16x16x32_bf16(af[i], bf[j], acc[i][j], 0, 0, 0);
        __builtin_amdgcn_s_setprio(0);

        // ---- counted gate: wait for s+1's loads only ----
        if (s + 1 < NS) {
            if (s + 2 < NS) asm volatile("s_waitcnt vmcnt(4)" ::: "memory");
            else            asm volatile("s_waitcnt vmcnt(0)" ::: "memory");
            __builtin_amdgcn_s_barrier();
        }
        slc++; if (slc == 3) slc = 0;
    }

    if (mode == 1) {   // final output: f32, row remap
        for (int j = 0; j < 4; j++) {
            int col = blockIdx.x * 128 + wn + j * 16 + lm;
            float bv = bias[col];
            for (int i = 0; i < 4; i++) {
                int row0 = blockIdx.y * 128 + wm + i * 16 + lg * 4;
                for (int r = 0; r < 4; r++) {
                    int row = row0 + r;
                    int orow = ((row & 1) << 11) + (row >> 1);
                    ((float*)C)[(size_t)orow * 2048 + col] = acc[i][j][r] + bv;
                }
            }
        }
        return;
    }

    // ---- mode 0: fused QKV scatter epilogue ----
    int ct = blockIdx.x;
    int nh = ct / 3, part = ct - nh * 3;
    float bscale = (part == 0) ? QSCALE : 1.0f;
    int rbase = blockIdx.y * 128;                 // global row base (= b*2048 + s0)
    int b = rbase >> 11;
    int s0 = rbase & 2047;

    if (part < 2) {   // q or k -> [bn][pos][hd]
        u16* dst0 = part ? kb : qb;
        for (int j = 0; j < 4; j++) {
            int hd = wn + j * 16 + lm;
            float bv = bias[ct * 128 + hd] * bscale;
            for (int i = 0; i < 4; i++) {
                for (int r = 0; r < 4; r++) {
                    int rl = wm + i * 16 + lg * 4 + r;       // local row 0..127
                    int s = s0 + rl;
                    int bn = (s & 1) * 16 + nh;
                    int pos = (b << 10) + (s >> 1);
                    dst0[((size_t)(bn * 2048 + pos)) * 128 + hd] = f2b(acc[i][j][r] + bv);
                }
            }
        }
    } else {          // v -> transpose via LDS -> vb[bn][hd][pos]
        u16 (*arr)[64][128] = (u16(*)[64][128])lds;   // [par][pos_local][hd] (32 KiB)
        __syncthreads();   // all waves done with ring reads
        for (int j = 0; j < 4; j++) {
            int hd = wn + j * 16 + lm;
            float bv = bias[ct * 128 + hd];
            for (int i = 0; i < 4; i++) {
                for (int r = 0; r < 4; r++) {
                    int rl = wm + i * 16 + lg * 4 + r;
                    arr[rl & 1][rl >> 1][hd] = f2b(acc[i][j][r] + bv);
                }
            }
        }
        __syncthreads();
        int hd = tid & 127, par = tid >> 7;
        int bn = par * 16 + nh;
        int pos0 = (b << 10) + (s0 >> 1);
        u16* dst = vb + ((size_t)(bn * 128 + hd)) * 2048 + pos0;
        for (int c = 0; c < 8; c++) {
            u16x8 w;
            for (int e = 0; e < 8; e++) w[e] = arr[par][c * 8 + e][hd];
            *(u16x8*)(dst + c * 8) = w;
        }
    }
}

// ---------------------------------------------------------------------------
// flash attention, scrambled (bn,pos) space.
//   - grid (16, 32) = 512 blocks -> 2 blocks/CU (80 KiB LDS); 4 waves x 32 q-rows
//   - K/V staged via global_load_lds DOUBLE-BUFFER: linear LDS dest +
//     inverse-swizzled per-lane global source (chunk ^= row&7); reads use the
//     same xor -> ~2-way conflicts, zero ds_write staging instructions
//   - counted vmcnt(8): next tile's 8 loads stay in flight across the barrier
//   - no-max softmax (shift 8 in alibi, log2e in q), row sums via ones-MFMA
//   - per-block k-range grows with qt; dispatch order interleaves long/short
// Writes ctx bf16 [pos*2+bn>>4][(bn&15)*128+hd].
// ---------------------------------------------------------------------------
__global__ __launch_bounds__(256) void attn(
    const u16* __restrict__ qb, const u16* __restrict__ kb,
    const u16* __restrict__ vb, const float* __restrict__ alibi,
    u16* __restrict__ ctx)
{
    __shared__ u16 Ks2[2][64 * 128];   // [k][hd] 16 chunks/row, src-preswizzled
    __shared__ u16 Vt2[2][128 * 64];   // [hd][k] 8 chunks/row, src-preswizzled
    __shared__ u16 Ps[4][32 * 64];     // per-wave P [q32][k64], xor-swizzled

    const int bn = blockIdx.y;
    const int qt = blockIdx.x;              // 0..15, 128 q-rows
    const int q0 = qt * 128;
    const int ktmax = 2 * qt + 1;

    const int tid = threadIdx.x, wave = tid >> 6, lane = tid & 63;
    const int lg = lane >> 4, lm = lane & 15;
    const int rxor = (lm & 7) * 8;          // read-side chunk swizzle (u16 units)
    const int qrow0 = q0 + wave * 32;

    const float* al = alibi + (bn & 15) * 2048;

    // ---- staging address precompute ----
    // K: instr i stages rows 16w+4i .. +3; lane L -> row-in-group rl=L>>4, phys chunk L&15
    const int krl = lane >> 4;                               // 0..3
    const u16* Kbase = kb + ((size_t)bn * 2048 + 16 * wave + krl) * 128;
    const int kco0 = ((lane & 15) ^ krl) * 8;                // i even: xor 4i=0
    const int kco1 = ((lane & 15) ^ (4 + krl)) * 8;          // i odd
    // V: instr i stages hd rows 32w+8i .. +7; lane L -> vl=L>>3, phys chunk L&7
    const int vl = lane >> 3;                                // 0..7
    const u16* Vbase = vb + ((size_t)(bn * 128 + 32 * wave) + vl) * 2048
                          + (((lane & 7) ^ vl) * 8);

    auto stage = [&](int buf, int kt) {
        size_t k0 = (size_t)kt * 64;
        u16* kd = &Ks2[buf][16 * wave * 128];
        for (int i = 0; i < 4; i++)
            async16(Kbase + (k0 + 4 * i) * 128 + ((i & 1) ? kco1 : kco0),
                    kd + 4 * i * 128);
        u16* vd = &Vt2[buf][32 * wave * 64];
        for (int i = 0; i < 4; i++)
            async16(Vbase + (size_t)i * 16384 + k0, vd + 8 * i * 64);
    };

    u16* ps = &Ps[wave][0];
    bf16x8 ones;
    {
        u16x8 t;
        for (int j = 0; j < 8; j++) t[j] = 0x3F80;   // bf16 1.0
        ones = *(bf16x8*)&t;
    }

    // Q fragments (log2e pre-folded into qb)
    bf16x8 qf[2][4];
    for (int f = 0; f < 2; f++) {
        const u16* qp = qb + ((size_t)bn * 2048 + qrow0 + f * 16 + lm) * 128 + lg * 8;
        for (int kc = 0; kc < 4; kc++) qf[f][kc] = *(const bf16x8*)(qp + kc * 32);
    }

    f32x4 o[2][9];
    for (int f = 0; f < 2; f++)
        for (int i = 0; i < 9; i++) o[f][i] = (f32x4){0.f, 0.f, 0.f, 0.f};

    stage(0, 0);

    for (int kt = 0; kt <= ktmax; kt++) {
        int buf = kt & 1;
        if (kt < ktmax) {
            stage(buf ^ 1, kt + 1);
            asm volatile("s_waitcnt vmcnt(8)" ::: "memory");   // kt's 8 loads done
        } else {
            asm volatile("s_waitcnt vmcnt(0)" ::: "memory");
        }
        __builtin_amdgcn_s_barrier();

        int k0 = kt * 64;
        bool act = (k0 <= qrow0 + 31);     // wave-uniform
        if (act) {
            const u16* KsB = &Ks2[buf][0];
            const u16* VtB = &Vt2[buf][0];

            // ---- QK^T: both q-frags share the K fragments ----
            f32x4 sc[2][4];
            for (int tc = 0; tc < 4; tc++) {
                const u16* kr = &KsB[(tc * 16 + lm) * 128];
                bf16x8 krf[4];
                for (int kc = 0; kc < 4; kc++)
                    krf[kc] = *(const bf16x8*)&kr[(kc * 32 + lg * 8) ^ rxor];
                for (int f = 0; f < 2; f++) {
                    f32x4 a = (f32x4){0.f, 0.f, 0.f, 0.f};
                    for (int kc = 0; kc < 4; kc++)
                        a = __builtin_amdgcn_mfma_f32_16x16x32_bf16(qf[f][kc], krf[kc], a, 0, 0, 0);
                    sc[f][tc] = a;
                }
            }

            // ---- alibi + causal mask + exp2 -> P (bf16, swizzled LDS) ----
            bool dz = (kt >= 2 * qt);
            for (int tc = 0; tc < 4; tc++) {
                int kg = k0 + tc * 16 + lm;
                float av = (al[kg] - 8.0f) * 1.4426950408889634f;
                for (int f = 0; f < 2; f++) {
                    for (int r = 0; r < 4; r++) {
                        float v = sc[f][tc][r] + av;
                        if (dz && kg > qrow0 + f * 16 + lg * 4 + r) v = -3e38f;
                        int row = f * 16 + lg * 4 + r;
                        ps[row * 64 + ((tc * 16 + lm) ^ ((row & 7) * 8))] =
                            f2b(__builtin_amdgcn_exp2f(v));
                    }
                }
            }

            // ---- PV: V fragments shared by both q-frags; 9th col = row sum ----
            for (int kc = 0; kc < 2; kc++) {
                bf16x8 pf[2];
                for (int f = 0; f < 2; f++)
                    pf[f] = *(const bf16x8*)&ps[(f * 16 + lm) * 64 + ((kc * 32 + lg * 8) ^ rxor)];
                for (int i = 0; i < 8; i++) {
                    bf16x8 vf = *(const bf16x8*)&VtB[(i * 16 + lm) * 64 + ((kc * 32 + lg * 8) ^ rxor)];
                    for (int f = 0; f < 2; f++)
                        o[f][i] = __builtin_amdgcn_mfma_f32_16x16x32_bf16(pf[f], vf, o[f][i], 0, 0, 0);
                }
                for (int f = 0; f < 2; f++)
                    o[f][8] = __builtin_amdgcn_mfma_f32_16x16x32_bf16(pf[f], ones, o[f][8], 0, 0, 0);
            }
        }
        __builtin_amdgcn_s_barrier();      // compute done; next iter may overwrite buf^1
    }

    for (int f = 0; f < 2; f++) {
        for (int r = 0; r < 4; r++) {
            float inv = 1.0f / o[f][8][r];
            int qg = qrow0 + f * 16 + lg * 4 + r;
            int row = qg * 2 + (bn >> 4);
            u16* crow = ctx + (size_t)row * 2048 + (bn & 15) * 128 + lm;
            for (int i = 0; i < 8; i++)
                crow[i * 16] = f2b(o[f][i][r] * inv);
        }
    }
}

// ---------------------------------------------------------------------------
// launch
// ---------------------------------------------------------------------------
extern "C" void kernel_launch(void* const* d_in, const int* in_sizes, int n_in,
                              void* d_out, int out_size, void* d_ws, size_t ws_size,
                              hipStream_t stream)
{
    const float* hs    = (const float*)d_in[0];   // [2,2048,2048]
    const float* alibi = (const float*)d_in[1];   // [16,1,2048]
    const float* wqkv  = (const float*)d_in[2];   // [6144,2048]
    const float* bqkv  = (const float*)d_in[3];   // [6144]
    const float* wd    = (const float*)d_in[4];   // [2048,2048]
    const float* bd    = (const float*)d_in[5];   // [2048]
    float* out = (float*)d_out;                   // [2,2048,2048] f32

    char* ws = (char*)d_ws;
    u16* wqkv_b = (u16*)(ws + 0);            // 25,165,824 B
    u16* hs_b   = (u16*)(ws + 25165824);     // 16,777,216 B
    u16* ctx    = (u16*)(ws + 41943040);     // 16,777,216 B (bf16 [4096][2048])
    u16* wd_b   = wqkv_b;                    // alias: wqkv dead after gemm1
    u16* qb     = (u16*)(ws + 92274688);     // [32][2048][128] bf16
    u16* kb     = (u16*)(ws + 109051904);
    u16* vb     = (u16*)(ws + 125829120);    // end = 142,606,336 B

    cvt_f32_bf16<<<8192,  256, 0, stream>>>(hs,   hs_b,   2097152);
    cvt_wqkv   <<<12288, 256, 0, stream>>>(wqkv, wqkv_b, 3145728);

    // QKV GEMM, 128x128-tile 3-slot ring, 3 blocks/CU, fused scatter epilogue
    gemm_ring<<<dim3(48, 32), 256, 0, stream>>>(hs_b, wqkv_b, bqkv, nullptr,
                                                qb, kb, vb, 0);

    cvt_f32_bf16<<<4096, 256, 0, stream>>>(wd, wd_b, 1048576);

    // flash attention: 512 blocks, 2/CU, async double-buffered K/V
    attn<<<dim3(16, 32), 256, 0, stream>>>(qb, kb, vb, alibi, ctx);

    // out = ctx @ wd^T + bd, rows remapped to [b][s][h]
    gemm_ring<<<dim3(16, 32), 256, 0, stream>>>(ctx, wd_b, bd, out,
                                                nullptr, nullptr, nullptr, 1);
}

// Round 5
// 401.755 us; speedup vs baseline: 1.1941x; 1.1941x over previous
//
#include <hip/hip_runtime.h>

typedef unsigned short u16;
typedef __bf16  bf16x8 __attribute__((ext_vector_type(8)));
typedef float   f32x4  __attribute__((ext_vector_type(4)));
typedef u16     u16x8  __attribute__((ext_vector_type(8)));
typedef u16     u16x4  __attribute__((ext_vector_type(4)));

#define QSCALE 0.12751744545f   // log2(e)/sqrt(128)

// ---------------------------------------------------------------------------
// helpers
// ---------------------------------------------------------------------------
__device__ __forceinline__ u16 f2b(float f) {               // f32 -> bf16 (RNE)
    unsigned u = __float_as_uint(f);
    unsigned r = u + 0x7FFFu + ((u >> 16) & 1u);
    return (u16)(r >> 16);
}
__device__ __forceinline__ void async16(const u16* g, u16* l) {
    // lane L's 16B land at (wave-uniform l) + L*16; global src addr is per-lane
    __builtin_amdgcn_global_load_lds(
        (__attribute__((address_space(1))) void*)(u16*)g,
        (__attribute__((address_space(3))) void*)l, 16, 0, 0);
}

// ---------------------------------------------------------------------------
// fp32 -> bf16 convert (float4 per thread)
// ---------------------------------------------------------------------------
__global__ void cvt_f32_bf16(const float* __restrict__ in, u16* __restrict__ out, int n4) {
    int i = blockIdx.x * blockDim.x + threadIdx.x;
    if (i >= n4) return;
    float4 f = ((const float4*)in)[i];
    u16x4 o;
    o[0] = f2b(f.x); o[1] = f2b(f.y); o[2] = f2b(f.z); o[3] = f2b(f.w);
    *(u16x4*)(out + (size_t)i * 4) = o;
}

// wqkv convert with q-row pre-scale folded in (rows with (row%384)<128 are q)
__global__ void cvt_wqkv(const float* __restrict__ in, u16* __restrict__ out, int n4) {
    int i = blockIdx.x * blockDim.x + threadIdx.x;
    if (i >= n4) return;
    int row = i >> 9;                       // 512 float4 per 2048-elem row
    float s = ((row % 384) < 128) ? QSCALE : 1.0f;
    float4 f = ((const float4*)in)[i];
    u16x4 o;
    o[0] = f2b(f.x * s); o[1] = f2b(f.y * s); o[2] = f2b(f.z * s); o[3] = f2b(f.w * s);
    *(u16x4*)(out + (size_t)i * 4) = o;
}

// ---------------------------------------------------------------------------
// QKV GEMM, 256x256 tile, 8-wave, 4-slot K32 ring, counted vmcnt, swizzled LDS.
// (reverted to the configuration measured at 140.0 us in three rounds)
// ---------------------------------------------------------------------------
__global__ __launch_bounds__(512, 2) void gemm_qkv(
    const u16* __restrict__ A, const u16* __restrict__ B,
    const float* __restrict__ bias,
    u16* __restrict__ qb, u16* __restrict__ kb, u16* __restrict__ vb)
{
    constexpr int K  = 2048;
    constexpr int NS = K / 32;              // 64 K-subtiles
    __shared__ u16 lds[65536];              // 128 KiB: 4 slots x (A 8192 + B 8192) u16

    const int tid = threadIdx.x, wave = tid >> 6, lane = tid & 63;
    const int lm = lane & 15, lg = lane >> 4;
    const int wr = wave >> 2, wc = wave & 3;

    const int rbase = blockIdx.y * 256;     // A row base   (M)
    const int cbase = blockIdx.x * 256;     // B row base   (N / out col)

    // ---- staging setup: 32 chunks (1 KiB each) per subtile; wave owns 4 ----
    const int srl = lane >> 2;                                  // row in chunk
    const int scs = ((lane & 3) ^ ((lane >> 3) & 3)) << 3;      // swizzled col (u16)
    const u16* sl0;
    int lbase;                               // u16 offset of wave's chunk 0 in a slot
    {
        int qq = (wave & 3) * 4;             // first chunk idx within A or B region
        if (wave < 4) { sl0 = A + (size_t)rbase * K; lbase = qq * 512; }
        else          { sl0 = B + (size_t)cbase * K; lbase = 8192 + qq * 512; }
        sl0 += (size_t)(qq * 16 + srl) * K + scs;
    }
    auto stage2 = [&](int s_, int c0) {      // issue 2 global_load_lds (1 KiB each)
        int slot = (s_ & 3) * 16384;
        size_t k0 = (size_t)s_ * 32;
        for (int c = c0; c < c0 + 2; c++)
            async16(sl0 + (size_t)c * 16 * K + k0, &lds[slot + lbase + c * 512]);
    };

    // ---- fragment read offsets (swizzle folds to a per-lane constant) ----
    const int coff = (lg ^ ((lm >> 1) & 3)) << 3;
    const int aoff = (wr * 128 + lm) * 32 + coff;
    const int boff = 8192 + (wc * 64 + lm) * 32 + coff;

    f32x4 acc[8][4];
    for (int m = 0; m < 8; m++)
        for (int n = 0; n < 4; n++)
            acc[m][n] = (f32x4){0.f, 0.f, 0.f, 0.f};

    // ---- prologue: stage subtiles 0..2, wait for subtile 0 (leave 8 in flight)
    stage2(0, 0); stage2(0, 2);
    stage2(1, 0); stage2(1, 2);
    stage2(2, 0); stage2(2, 2);
    asm volatile("s_waitcnt vmcnt(8)" ::: "memory");
    __builtin_amdgcn_s_barrier();

    for (int s = 0; s < NS; s++) {
        const u16* sl = &lds[(s & 3) * 16384];
        bf16x8 af[4], bf[4];

        // ---- phase 1: B n0-3 + A m0-3, stage half of subtile s+3 ----
        for (int n = 0; n < 4; n++) bf[n] = *(const bf16x8*)&sl[boff + n * 512];
        for (int m = 0; m < 4; m++) af[m] = *(const bf16x8*)&sl[aoff + m * 512];
        if (s + 3 < NS) stage2(s + 3, 0);
        __builtin_amdgcn_s_barrier();
        __builtin_amdgcn_s_setprio(1);
        for (int m = 0; m < 4; m++)
            for (int n = 0; n < 4; n++)
                acc[m][n] = __builtin_amdgcn_mfma_f32_16x16x32_bf16(af[m], bf[n], acc[m][n], 0, 0, 0);
        __builtin_amdgcn_s_setprio(0);
        __builtin_amdgcn_s_barrier();

        // ---- phase 2: A m4-7 (B reused), stage other half of s+3 ----
        for (int m = 0; m < 4; m++) af[m] = *(const bf16x8*)&sl[aoff + (m + 4) * 512];
        if (s + 3 < NS) stage2(s + 3, 2);
        __builtin_amdgcn_s_barrier();
        __builtin_amdgcn_s_setprio(1);
        for (int m = 0; m < 4; m++)
            for (int n = 0; n < 4; n++)
                acc[m + 4][n] = __builtin_amdgcn_mfma_f32_16x16x32_bf16(af[m], bf[n], acc[m + 4][n], 0, 0, 0);
        __builtin_amdgcn_s_setprio(0);

        // ---- end-of-subtile gate: counted, never 0 until the tail ----
        if (s + 1 < NS) {
            if (s < NS - 3)       asm volatile("s_waitcnt vmcnt(8)" ::: "memory");
            else if (s == NS - 3) asm volatile("s_waitcnt vmcnt(4)" ::: "memory");
            else                  asm volatile("s_waitcnt vmcnt(0)" ::: "memory");
            __builtin_amdgcn_s_barrier();
        }
    }

    // ---- epilogue: fused QKV scatter ----
    __syncthreads();                         // ring buffers dead; also drains

    const int ct   = (cbase >> 7) + (wc >> 1);      // wave's 128-col group
    const int nh   = ct / 3, part = ct - nh * 3;
    const int hd0  = (wc & 1) * 64;                 // head-dim base of wave's 64 cols
    const int posb = (rbase >> 11) << 10;           // b * 1024
    const int sblk = (rbase & 2047) + wr * 128;     // s base of wave's 128 rows

    if (part < 2) {          // q or k -> [bn][pos][hd]
        u16* dst0 = part ? kb : qb;
        const float bsc = part ? 1.0f : QSCALE;
        for (int n = 0; n < 4; n++) {
            int hd = hd0 + n * 16 + lm;
            float bv = bias[ct * 128 + hd] * bsc;
            for (int m = 0; m < 8; m++) {
                for (int r = 0; r < 4; r++) {
                    int s_  = sblk + m * 16 + lg * 4 + r;
                    int bn  = (s_ & 1) * 16 + nh;
                    int pos = posb + (s_ >> 1);
                    dst0[((size_t)(bn * 2048 + pos)) * 128 + hd] = f2b(acc[m][n][r] + bv);
                }
            }
        }
    } else {                 // v -> per-wave LDS transpose -> vb[bn][hd][pos]
        u16* scr = &lds[wave * 8192];        // [128 rows][64 hd]
        for (int n = 0; n < 4; n++) {
            int hdl = n * 16 + lm;
            float bv = bias[ct * 128 + hd0 + hdl];
            for (int m = 0; m < 8; m++)
                for (int r = 0; r < 4; r++)
                    scr[(m * 16 + lg * 4 + r) * 64 + hdl] = f2b(acc[m][n][r] + bv);
        }
        int pos0 = posb + (sblk >> 1);
        for (int par = 0; par < 2; par++) {
            int bn = par * 16 + nh;
            u16* dst = vb + ((size_t)(bn * 128 + hd0 + lane)) * 2048 + pos0;
            for (int p8 = 0; p8 < 8; p8++) {
                u16x8 w;
                for (int e = 0; e < 8; e++)
                    w[e] = scr[(2 * (p8 * 8 + e) + par) * 64 + lane];
                *(u16x8*)(dst + p8 * 8) = w;
            }
        }
    }
}

// ---------------------------------------------------------------------------
// bf16 NT GEMM: C = A[M,K] * B[N,K]^T + bias   (128x128 tile, BK=64, 2 panels)
// mode 1: store f32 with row remap orow = (row&1)*2048 + (row>>1)  (final out)
// (reverted to the r0-composite version)
// ---------------------------------------------------------------------------
__global__ __launch_bounds__(256) void gemm_bt(
    const u16* __restrict__ A, const u16* __restrict__ B,
    const float* __restrict__ bias, void* __restrict__ C,
    int M, int N, int K)
{
    __shared__ u16 smem[16384];          // 32 KB: As | Bs
    u16* As = smem;                      // [p][row][32k] : p*4096 + row*32 + kk
    u16* Bs = smem + 8192;

    int tid = threadIdx.x, wave = tid >> 6, lane = tid & 63;
    int lg = lane >> 4, lm = lane & 15;
    int wm = (wave & 1) * 64, wn = (wave >> 1) * 64;

    const u16* Ab = A + (size_t)(blockIdx.y * 128) * K;
    const u16* Bb = B + (size_t)(blockIdx.x * 128) * K;

    f32x4 acc[4][4];
    for (int i = 0; i < 4; i++)
        for (int j = 0; j < 4; j++)
            acc[i][j] = (f32x4){0.f, 0.f, 0.f, 0.f};

    int srow = (lane >> 2), skq = (lane & 3) * 8;   // lane -> row/k within 1KB chunk

    for (int k0 = 0; k0 < K; k0 += 64) {
        __syncthreads();
        for (int cc = wave; cc < 16; cc += 4) {
            int p = cc >> 3, c = cc & 7;
            int row = c * 16 + srow;
            size_t off = (size_t)row * K + k0 + p * 32 + skq;
            async16(Ab + off, &As[p * 4096 + c * 512]);
            async16(Bb + off, &Bs[p * 4096 + c * 512]);
        }
        __syncthreads();   // compiler drains vmcnt before barrier

        for (int p = 0; p < 2; p++) {
            bf16x8 af[4], bf[4];
            for (int i = 0; i < 4; i++) af[i] = *(const bf16x8*)&As[p * 4096 + (wm + i * 16 + lm) * 32 + lg * 8];
            for (int j = 0; j < 4; j++) bf[j] = *(const bf16x8*)&Bs[p * 4096 + (wn + j * 16 + lm) * 32 + lg * 8];
            for (int i = 0; i < 4; i++)
                for (int j = 0; j < 4; j++)
                    acc[i][j] = __builtin_amdgcn_mfma_f32_16x16x32_bf16(af[i], bf[j], acc[i][j], 0, 0, 0);
        }
    }

    // final output: f32, row remap
    for (int j = 0; j < 4; j++) {
        int col = blockIdx.x * 128 + wn + j * 16 + lm;
        float bv = bias[col];
        for (int i = 0; i < 4; i++) {
            int row0 = blockIdx.y * 128 + wm + i * 16 + lg * 4;
            for (int r = 0; r < 4; r++) {
                int row = row0 + r;
                int orow = ((row & 1) << 11) + (row >> 1);
                ((float*)C)[(size_t)orow * N + col] = acc[i][j][r] + bv;
            }
        }
    }
}

// ---------------------------------------------------------------------------
// flash attention, scrambled (bn,pos) space.
//   - r4 structure (async gload_lds double-buffer, counted vmcnt(8)) with ONE
//     change: balanced block->(bn,qt) map. Co-resident blocks i and i+256
//     (linear dispatch) get complementary qt (y bit4 flips), so every CU's
//     two blocks sum to 36 k-tiles -> no makespan imbalance (r4: 6.2% occ).
//   - bn = (y&15) | ((x&1)<<4); qh = (x>>1)&7; qt = (y>>4) ? 15-qh : qh
// Writes ctx bf16 [pos*2+bn>>4][(bn&15)*128+hd].
// ---------------------------------------------------------------------------
__global__ __launch_bounds__(256) void attn(
    const u16* __restrict__ qb, const u16* __restrict__ kb,
    const u16* __restrict__ vb, const float* __restrict__ alibi,
    u16* __restrict__ ctx)
{
    __shared__ u16 Ks2[2][64 * 128];   // [k][hd] 16 chunks/row, src-preswizzled
    __shared__ u16 Vt2[2][128 * 64];   // [hd][k] 8 chunks/row, src-preswizzled
    __shared__ u16 Ps[4][32 * 64];     // per-wave P [q32][k64], xor-swizzled

    const int x = blockIdx.x, y = blockIdx.y;
    const int bn = (y & 15) | ((x & 1) << 4);
    const int qh = (x >> 1) & 7;
    const int qt = (y >> 4) ? (15 - qh) : qh;       // 0..15, 128 q-rows
    const int q0 = qt * 128;
    const int ktmax = 2 * qt + 1;

    const int tid = threadIdx.x, wave = tid >> 6, lane = tid & 63;
    const int lg = lane >> 4, lm = lane & 15;
    const int rxor = (lm & 7) * 8;          // read-side chunk swizzle (u16 units)
    const int qrow0 = q0 + wave * 32;

    const float* al = alibi + (bn & 15) * 2048;

    // ---- staging address precompute ----
    // K: instr i stages rows 16w+4i .. +3; lane L -> row-in-group rl=L>>4, phys chunk L&15
    const int krl = lane >> 4;                               // 0..3
    const u16* Kbase = kb + ((size_t)bn * 2048 + 16 * wave + krl) * 128;
    const int kco0 = ((lane & 15) ^ krl) * 8;                // i even: xor 4i=0
    const int kco1 = ((lane & 15) ^ (4 + krl)) * 8;          // i odd
    // V: instr i stages hd rows 32w+8i .. +7; lane L -> vl=L>>3, phys chunk L&7
    const int vl = lane >> 3;                                // 0..7
    const u16* Vbase = vb + ((size_t)(bn * 128 + 32 * wave) + vl) * 2048
                          + (((lane & 7) ^ vl) * 8);

    auto stage = [&](int buf, int kt) {
        size_t k0 = (size_t)kt * 64;
        u16* kd = &Ks2[buf][16 * wave * 128];
        for (int i = 0; i < 4; i++)
            async16(Kbase + (k0 + 4 * i) * 128 + ((i & 1) ? kco1 : kco0),
                    kd + 4 * i * 128);
        u16* vd = &Vt2[buf][32 * wave * 64];
        for (int i = 0; i < 4; i++)
            async16(Vbase + (size_t)i * 16384 + k0, vd + 8 * i * 64);
    };

    u16* ps = &Ps[wave][0];
    bf16x8 ones;
    {
        u16x8 t;
        for (int j = 0; j < 8; j++) t[j] = 0x3F80;   // bf16 1.0
        ones = *(bf16x8*)&t;
    }

    // Q fragments (log2e pre-folded into qb)
    bf16x8 qf[2][4];
    for (int f = 0; f < 2; f++) {
        const u16* qp = qb + ((size_t)bn * 2048 + qrow0 + f * 16 + lm) * 128 + lg * 8;
        for (int kc = 0; kc < 4; kc++) qf[f][kc] = *(const bf16x8*)(qp + kc * 32);
    }

    f32x4 o[2][9];
    for (int f = 0; f < 2; f++)
        for (int i = 0; i < 9; i++) o[f][i] = (f32x4){0.f, 0.f, 0.f, 0.f};

    stage(0, 0);

    for (int kt = 0; kt <= ktmax; kt++) {
        int buf = kt & 1;
        if (kt < ktmax) {
            stage(buf ^ 1, kt + 1);
            asm volatile("s_waitcnt vmcnt(8)" ::: "memory");   // kt's 8 loads done
        } else {
            asm volatile("s_waitcnt vmcnt(0)" ::: "memory");
        }
        __builtin_amdgcn_s_barrier();

        int k0 = kt * 64;
        bool act = (k0 <= qrow0 + 31);     // wave-uniform
        if (act) {
            const u16* KsB = &Ks2[buf][0];
            const u16* VtB = &Vt2[buf][0];

            // ---- QK^T: both q-frags share the K fragments ----
            f32x4 sc[2][4];
            for (int tc = 0; tc < 4; tc++) {
                const u16* kr = &KsB[(tc * 16 + lm) * 128];
                bf16x8 krf[4];
                for (int kc = 0; kc < 4; kc++)
                    krf[kc] = *(const bf16x8*)&kr[(kc * 32 + lg * 8) ^ rxor];
                for (int f = 0; f < 2; f++) {
                    f32x4 a = (f32x4){0.f, 0.f, 0.f, 0.f};
                    for (int kc = 0; kc < 4; kc++)
                        a = __builtin_amdgcn_mfma_f32_16x16x32_bf16(qf[f][kc], krf[kc], a, 0, 0, 0);
                    sc[f][tc] = a;
                }
            }

            // ---- alibi + causal mask + exp2 -> P (bf16, swizzled LDS) ----
            bool dz = (kt >= 2 * qt);
            for (int tc = 0; tc < 4; tc++) {
                int kg = k0 + tc * 16 + lm;
                float av = (al[kg] - 8.0f) * 1.4426950408889634f;
                for (int f = 0; f < 2; f++) {
                    for (int r = 0; r < 4; r++) {
                        float v = sc[f][tc][r] + av;
                        if (dz && kg > qrow0 + f * 16 + lg * 4 + r) v = -3e38f;
                        int row = f * 16 + lg * 4 + r;
                        ps[row * 64 + ((tc * 16 + lm) ^ ((row & 7) * 8))] =
                            f2b(__builtin_amdgcn_exp2f(v));
                    }
                }
            }

            // ---- PV: V fragments shared by both q-frags; 9th col = row sum ----
            for (int kc = 0; kc < 2; kc++) {
                bf16x8 pf[2];
                for (int f = 0; f < 2; f++)
                    pf[f] = *(const bf16x8*)&ps[(f * 16 + lm) * 64 + ((kc * 32 + lg * 8) ^ rxor)];
                for (int i = 0; i < 8; i++) {
                    bf16x8 vf = *(const bf16x8*)&VtB[(i * 16 + lm) * 64 + ((kc * 32 + lg * 8) ^ rxor)];
                    for (int f = 0; f < 2; f++)
                        o[f][i] = __builtin_amdgcn_mfma_f32_16x16x32_bf16(pf[f], vf, o[f][i], 0, 0, 0);
                }
                for (int f = 0; f < 2; f++)
                    o[f][8] = __builtin_amdgcn_mfma_f32_16x16x32_bf16(pf[f], ones, o[f][8], 0, 0, 0);
            }
        }
        __builtin_amdgcn_s_barrier();      // compute done; next iter may overwrite buf^1
    }

    for (int f = 0; f < 2; f++) {
        for (int r = 0; r < 4; r++) {
            float inv = 1.0f / o[f][8][r];
            int qg = qrow0 + f * 16 + lg * 4 + r;
            int row = qg * 2 + (bn >> 4);
            u16* crow = ctx + (size_t)row * 2048 + (bn & 15) * 128 + lm;
            for (int i = 0; i < 8; i++)
                crow[i * 16] = f2b(o[f][i][r] * inv);
        }
    }
}

// ---------------------------------------------------------------------------
// launch
// ---------------------------------------------------------------------------
extern "C" void kernel_launch(void* const* d_in, const int* in_sizes, int n_in,
                              void* d_out, int out_size, void* d_ws, size_t ws_size,
                              hipStream_t stream)
{
    const float* hs    = (const float*)d_in[0];   // [2,2048,2048]
    const float* alibi = (const float*)d_in[1];   // [16,1,2048]
    const float* wqkv  = (const float*)d_in[2];   // [6144,2048]
    const float* bqkv  = (const float*)d_in[3];   // [6144]
    const float* wd    = (const float*)d_in[4];   // [2048,2048]
    const float* bd    = (const float*)d_in[5];   // [2048]
    float* out = (float*)d_out;                   // [2,2048,2048] f32

    char* ws = (char*)d_ws;
    u16* wqkv_b = (u16*)(ws + 0);            // 25,165,824 B
    u16* hs_b   = (u16*)(ws + 25165824);     // 16,777,216 B
    u16* ctx    = (u16*)(ws + 41943040);     // 16,777,216 B (bf16 [4096][2048])
    u16* wd_b   = wqkv_b;                    // alias: wqkv dead after gemm1
    u16* qb     = (u16*)(ws + 92274688);     // [32][2048][128] bf16
    u16* kb     = (u16*)(ws + 109051904);
    u16* vb     = (u16*)(ws + 125829120);    // end = 142,606,336 B

    cvt_f32_bf16<<<8192,  256, 0, stream>>>(hs,   hs_b,   2097152);
    cvt_wqkv   <<<12288, 256, 0, stream>>>(wqkv, wqkv_b, 3145728);

    // QKV GEMM, 256x256-tile ring schedule with fused scatter epilogue
    gemm_qkv<<<dim3(24, 16), 512, 0, stream>>>(hs_b, wqkv_b, bqkv, qb, kb, vb);

    cvt_f32_bf16<<<4096, 256, 0, stream>>>(wd, wd_b, 1048576);

    // flash attention: 512 blocks, balanced (bn,qt) map, async double-buffer
    attn<<<dim3(16, 32), 256, 0, stream>>>(qb, kb, vb, alibi, ctx);

    // out = ctx @ wd^T + bd, rows remapped to [b][s][h]
    gemm_bt<<<dim3(16, 32), 256, 0, stream>>>(ctx, wd_b, bd, out, 4096, 2048, 2048);
}